// Round 1
// baseline (751.926 us; speedup 1.0000x reference)
//
#include <hip/hip_runtime.h>
#include <hip/hip_bf16.h>

// CubicalLayer: gather birth/death filtration values from flattened 512^3
// volume via persistence-pair indices; zero out pairs with |d-b| <= 0.
//
// out layout: dgm0 (P0 pairs * 2 floats) followed by dgm1 (P1 pairs * 2).

__global__ __launch_bounds__(256) void gather_diagram_kernel(
    const float* __restrict__ Xflat,
    const int* __restrict__ idx,   // 2*P interleaved (birth, death) indices
    float* __restrict__ out,       // P * 2 floats
    int P) {
    int p = blockIdx.x * blockDim.x + threadIdx.x;
    if (p >= P) return;
    // birth/death indices are adjacent -> single coalesced 8B load
    int2 ij = reinterpret_cast<const int2*>(idx)[p];
    float b = Xflat[ij.x];
    float d = Xflat[ij.y];
    bool keep = fabsf(d - b) > 0.0f;   // min_pers = 0.0
    float2 o;
    o.x = keep ? b : 0.0f;
    o.y = keep ? d : 0.0f;
    reinterpret_cast<float2*>(out)[p] = o;
}

extern "C" void kernel_launch(void* const* d_in, const int* in_sizes, int n_in,
                              void* d_out, int out_size, void* d_ws, size_t ws_size,
                              hipStream_t stream) {
    const float* X        = (const float*)d_in[0];
    const int*   indices0 = (const int*)d_in[1];
    const int*   indices1 = (const int*)d_in[2];
    float*       out      = (float*)d_out;

    const int P0 = in_sizes[1] / 2;   // pairs in dim 0
    const int P1 = in_sizes[2] / 2;   // pairs in dim 1

    const int block = 256;
    gather_diagram_kernel<<<(P0 + block - 1) / block, block, 0, stream>>>(
        X, indices0, out, P0);
    gather_diagram_kernel<<<(P1 + block - 1) / block, block, 0, stream>>>(
        X, indices1, out + (size_t)P0 * 2, P1);
}

// Round 3
// 748.495 us; speedup vs baseline: 1.0046x; 1.0046x over previous
//
#include <hip/hip_runtime.h>
#include <hip/hip_bf16.h>

// CubicalLayer: gather birth/death filtration values from flattened 512^3
// volume via persistence-pair indices; zero out pairs with death == birth
// (min_pers = 0.0). out = dgm0 (P0*2 floats) ++ dgm1 (P1*2 floats).
//
// Random-gather bound. Strategy: 16 independent gathers in flight per
// thread (latency hiding via ILP), 16B coalesced index/output traffic,
// non-temporal on the streaming index/output paths so L2 stays available
// for gather-line reuse.
//
// NOTE: __builtin_nontemporal_* requires Clang ext_vector_type, not the
// HIP_vector_type structs (int4/float4) — hence the typedefs.

typedef int   v4i __attribute__((ext_vector_type(4)));
typedef float v4f __attribute__((ext_vector_type(4)));

__global__ __launch_bounds__(256) void gather_diagram_kernel(
    const float* __restrict__ X,
    const int* __restrict__ idx0,   // 2*P0 interleaved (birth, death)
    const int* __restrict__ idx1,   // 2*P1
    float* __restrict__ out,
    int n4_0,      // P0/2 : number of 4-int chunks in idx0
    int n4_total)  // (P0+P1)/2 : total 4-int chunks
{
    constexpr int C = 4;  // 4-int chunks per thread -> 16 gathers in flight
    const int tid    = blockIdx.x * blockDim.x + threadIdx.x;
    const int stride = gridDim.x * blockDim.x;

    int  c[C];
    v4i  ij[C];
    bool ok[C];
    #pragma unroll
    for (int j = 0; j < C; ++j) {
        c[j]  = tid + j * stride;
        ok[j] = c[j] < n4_total;
        int cc = ok[j] ? c[j] : 0;
        const v4i* p = (cc < n4_0)
            ? reinterpret_cast<const v4i*>(idx0) + cc
            : reinterpret_cast<const v4i*>(idx1) + (cc - n4_0);
        ij[j] = __builtin_nontemporal_load(p);
    }

    float v[C][4];
    #pragma unroll
    for (int j = 0; j < C; ++j) {
        v[j][0] = X[ij[j].x];
        v[j][1] = X[ij[j].y];
        v[j][2] = X[ij[j].z];
        v[j][3] = X[ij[j].w];
    }

    #pragma unroll
    for (int j = 0; j < C; ++j) {
        bool k0 = v[j][1] != v[j][0];   // |d-b| > 0  <=>  d != b (no NaNs)
        bool k1 = v[j][3] != v[j][2];
        v4f o;
        o.x = k0 ? v[j][0] : 0.0f;
        o.y = k0 ? v[j][1] : 0.0f;
        o.z = k1 ? v[j][2] : 0.0f;
        o.w = k1 ? v[j][3] : 0.0f;
        if (ok[j])
            __builtin_nontemporal_store(o, reinterpret_cast<v4f*>(out) + c[j]);
    }
}

extern "C" void kernel_launch(void* const* d_in, const int* in_sizes, int n_in,
                              void* d_out, int out_size, void* d_ws, size_t ws_size,
                              hipStream_t stream) {
    const float* X        = (const float*)d_in[0];
    const int*   indices0 = (const int*)d_in[1];
    const int*   indices1 = (const int*)d_in[2];
    float*       out      = (float*)d_out;

    const int n4_0     = in_sizes[1] / 4;                   // 4-int chunks in idx0
    const int n4_total = (in_sizes[1] + in_sizes[2]) / 4;   // total 4-int chunks

    constexpr int C = 4, BLOCK = 256;
    const int threads_needed = (n4_total + C - 1) / C;
    const int blocks = (threads_needed + BLOCK - 1) / BLOCK;

    gather_diagram_kernel<<<blocks, BLOCK, 0, stream>>>(
        X, indices0, indices1, out, n4_0, n4_total);
}